// Round 5
// baseline (137.480 us; speedup 1.0000x reference)
//
#include <hip/hip_runtime.h>

#define NTYPES 11
#define BLOCK  256
#define ITEMS  8
#define CHUNK  (BLOCK * ITEMS)   // 2048 atoms per block
#define MAXCH  32                // max scan chunks (B <= 2048)

// ---------------------------------------------------------------------------
// Kernel 1: histogram + full in-block stable ranking.
// Outputs: bc[t*B+b] = per-block per-type counts, and meta[i] (u16) =
// (local type-sorted slot within block) | (type << 11).
// Moves all shuffle-scan ranking work out of the HBM-heavy scatter kernel.
// ---------------------------------------------------------------------------
__global__ __launch_bounds__(BLOCK) void hist_kernel(
    const int* __restrict__ types, int N, int B, int* __restrict__ bc,
    unsigned short* __restrict__ meta) {
  __shared__ int wtot[NTYPES][4];
  __shared__ int shOff[NTYPES];
  const int tid = threadIdx.x;
  const int b = blockIdx.x;
  const int lane = tid & 63;
  const int wave = tid >> 6;
  const int run = b * CHUNK + tid * ITEMS;
  const bool active = (run < N);

  int ty[ITEMS];
  int cnt[NTYPES];
#pragma unroll
  for (int t = 0; t < NTYPES; ++t) cnt[t] = 0;
#pragma unroll
  for (int k = 0; k < ITEMS; ++k) ty[k] = -1;

  if (active) {
    const int4* p = (const int4*)(types + run);
    int4 a0 = p[0], a1 = p[1];
    int tt[ITEMS] = {a0.x, a0.y, a0.z, a0.w, a1.x, a1.y, a1.z, a1.w};
#pragma unroll
    for (int k = 0; k < ITEMS; ++k) ty[k] = tt[k];
#pragma unroll
    for (int k = 0; k < ITEMS; ++k) {
#pragma unroll
      for (int t = 0; t < NTYPES; ++t) cnt[t] += (ty[k] == t) ? 1 : 0;
    }
  }

  // Wave-level stable exclusive scan per type.
  int rank[NTYPES];
#pragma unroll
  for (int t = 0; t < NTYPES; ++t) {
    int incl = cnt[t];
#pragma unroll
    for (int o = 1; o < 64; o <<= 1) {
      int v = __shfl_up(incl, o);
      if (lane >= o) incl += v;
    }
    if (lane == 63) wtot[t][wave] = incl;
    rank[t] = incl - cnt[t];
  }
  __syncthreads();

  if (tid < NTYPES) {
    int loc = 0;
    for (int u = 0; u < tid; ++u)
      loc += wtot[u][0] + wtot[u][1] + wtot[u][2] + wtot[u][3];
    shOff[tid] = loc;
    bc[tid * B + b] =
        wtot[tid][0] + wtot[tid][1] + wtot[tid][2] + wtot[tid][3];
  }
  __syncthreads();

#pragma unroll
  for (int t = 0; t < NTYPES; ++t) {
    int wb = 0;
#pragma unroll
    for (int w = 0; w < 3; ++w) wb += (w < wave) ? wtot[t][w] : 0;
    rank[t] += wb + shOff[t];
  }

  if (active) {
    unsigned int m[ITEMS];
#pragma unroll
    for (int k = 0; k < ITEMS; ++k) {
      const int t0 = ty[k];
      int slot = 0;
#pragma unroll
      for (int t = 0; t < NTYPES; ++t) {
        if (t0 == t) {
          slot = rank[t];
          rank[t] += 1;
        }
      }
      m[k] = (unsigned int)(slot | (t0 << 11));
    }
    int4 mv;
    mv.x = (int)(m[0] | (m[1] << 16));
    mv.y = (int)(m[2] | (m[3] << 16));
    mv.z = (int)(m[4] | (m[5] << 16));
    mv.w = (int)(m[6] | (m[7] << 16));
    *(int4*)(meta + run) = mv;
  }
}

// ---------------------------------------------------------------------------
// Kernel 2: one block, 11 waves; wave t scans type t's block-counts.
// Writes gBase[t*B+b] = offs[t] + exclusive-scan(bc[t]) — the global atom
// base for (type t, block b). Counts/offsets as FLOATS into d_out tail.
// ---------------------------------------------------------------------------
__global__ __launch_bounds__(NTYPES * 64) void scan_kernel(
    const int* __restrict__ bc, int B, int* __restrict__ gBase,
    float* __restrict__ outTail) {
  __shared__ int totals[NTYPES];
  __shared__ int offsSh[NTYPES];
  const int lane = threadIdx.x & 63;
  const int t = threadIdx.x >> 6;
  const int nch = (B + 63) >> 6;

  int x[MAXCH], ex[MAXCH];
#pragma unroll
  for (int c = 0; c < MAXCH; ++c) {
    const int idx = c * 64 + lane;
    x[c] = (c < nch && idx < B) ? bc[t * B + idx] : 0;
  }

  int carry = 0;
#pragma unroll
  for (int c = 0; c < MAXCH; ++c) {
    if (c >= nch) break;
    int incl = x[c];
#pragma unroll
    for (int o = 1; o < 64; o <<= 1) {
      int v = __shfl_up(incl, o);
      if (lane >= o) incl += v;
    }
    ex[c] = carry + incl - x[c];
    carry += __shfl(incl, 63);
  }
  if (lane == 0) totals[t] = carry;
  __syncthreads();

  if (threadIdx.x == 0) {
    int off = 0;
    for (int u = 0; u < NTYPES; ++u) {
      const int c = totals[u];
      offsSh[u] = off;
      outTail[u] = (float)c;            // counts (as float values)
      outTail[NTYPES + u] = (float)off; // offsets (as float values)
      off += c;
    }
  }
  __syncthreads();

  const int offt = offsSh[t];
#pragma unroll
  for (int c = 0; c < MAXCH; ++c) {
    if (c >= nch) break;
    const int idx = c * 64 + lane;
    if (idx < B) gBase[t * B + idx] = ex[c] + offt;
  }
}

// ---------------------------------------------------------------------------
// Kernel 3: scatter. No ranking — slots come precomputed in meta.
// Wave 0 lanes 0..10 derive local bucket offsets + global deltas via an
// 11-lane shfl scan; all threads stage coords type-sorted in LDS; single
// barrier; coalesced contiguous copy-out per type segment.
// ---------------------------------------------------------------------------
__global__ __launch_bounds__(BLOCK) void scatter_kernel(
    const float* __restrict__ coords, const unsigned short* __restrict__ meta,
    const int* __restrict__ bc, const int* __restrict__ gBase, int N, int B,
    float* __restrict__ out) {
  __shared__ float shC[CHUNK * 3];   // 24 KB type-sorted coords
  __shared__ int shOffA[NTYPES + 1]; // local bucket offsets (exclusive)
  __shared__ int shDelta[NTYPES];    // 3*(globalBase[t] - shOffA[t])

  const int tid = threadIdx.x;
  const int b = blockIdx.x;
  const int lane = tid & 63;
  const int wave = tid >> 6;
  const int run = b * CHUNK + tid * ITEMS;
  const bool active = (run < N);

  // Wave 0: per-block bucket offset math (11 lanes of real data).
  if (wave == 0) {
    int ct = 0, gt = 0;
    if (lane < NTYPES) {
      ct = bc[lane * B + b];
      gt = gBase[lane * B + b];
    }
    int incl = ct;
#pragma unroll
    for (int o = 1; o < 16; o <<= 1) {
      int v = __shfl_up(incl, o);
      if (lane >= o) incl += v;
    }
    const int excl = incl - ct;
    if (lane < NTYPES) {
      shOffA[lane] = excl;
      shDelta[lane] = 3 * (gt - excl);
    }
    if (lane == NTYPES - 1) shOffA[NTYPES] = incl;  // block total
  }

  if (active) {
    const int4 mv = *(const int4*)(meta + run);
    int slot[ITEMS];
    slot[0] = mv.x & 0x7FF;
    slot[1] = (mv.x >> 16) & 0x7FF;
    slot[2] = mv.y & 0x7FF;
    slot[3] = (mv.y >> 16) & 0x7FF;
    slot[4] = mv.z & 0x7FF;
    slot[5] = (mv.z >> 16) & 0x7FF;
    slot[6] = mv.w & 0x7FF;
    slot[7] = (mv.w >> 16) & 0x7FF;

    float c[ITEMS * 3];
    const float4* cp = (const float4*)(coords + (size_t)run * 3);
#pragma unroll
    for (int q = 0; q < (ITEMS * 3) / 4; ++q) {
      float4 v = cp[q];
      c[4 * q + 0] = v.x;
      c[4 * q + 1] = v.y;
      c[4 * q + 2] = v.z;
      c[4 * q + 3] = v.w;
    }
#pragma unroll
    for (int k = 0; k < ITEMS; ++k) {
      shC[3 * slot[k] + 0] = c[3 * k + 0];
      shC[3 * slot[k] + 1] = c[3 * k + 1];
      shC[3 * slot[k] + 2] = c[3 * k + 2];
    }
  }
  __syncthreads();

  // Coalesced copy-out: slot s -> global float index 3*s + delta3[type(s)].
  const int total = shOffA[NTYPES];
  int offr[NTYPES];
  int dlt[NTYPES];
#pragma unroll
  for (int t = 0; t < NTYPES; ++t) {
    offr[t] = shOffA[t];
    dlt[t] = shDelta[t];
  }
#pragma unroll
  for (int k = 0; k < ITEMS; ++k) {
    const int s = k * BLOCK + tid;
    if (s < total) {
      int d = dlt[0];
#pragma unroll
      for (int t = 1; t < NTYPES; ++t) d = (s >= offr[t]) ? dlt[t] : d;
      const int src = 3 * s;
      out[src + d + 0] = shC[src + 0];
      out[src + d + 1] = shC[src + 1];
      out[src + d + 2] = shC[src + 2];
    }
  }
}

extern "C" void kernel_launch(void* const* d_in, const int* in_sizes, int n_in,
                              void* d_out, int out_size, void* d_ws,
                              size_t ws_size, hipStream_t stream) {
  const float* coords = (const float*)d_in[0];
  const int* types = (const int*)d_in[1];
  const int N = in_sizes[1];              // 4,000,000 atoms
  const int B = (N + CHUNK - 1) / CHUNK;  // 1954 blocks

  const int bcElems = ((NTYPES * B + 63) / 64) * 64;  // padded, keeps 16B align
  int* bc = (int*)d_ws;                   // [NTYPES * B]
  int* gBase = bc + bcElems;              // [NTYPES * B]
  unsigned short* meta = (unsigned short*)(gBase + bcElems);  // [N] u16
  float* out = (float*)d_out;
  float* outTail = out + (size_t)3 * N;   // counts then offsets, as floats

  hist_kernel<<<B, BLOCK, 0, stream>>>(types, N, B, bc, meta);
  scan_kernel<<<1, NTYPES * 64, 0, stream>>>(bc, B, gBase, outTail);
  scatter_kernel<<<B, BLOCK, 0, stream>>>(coords, meta, bc, gBase, N, B, out);
}